// Round 9
// baseline (102.165 us; speedup 1.0000x reference)
//
#include <hip/hip_runtime.h>

// WeatherLSTM: B=4096 indep. sequences, T=512 steps, H=10, I=O=1.
// R8: aligned scalar layout (lane = hidden unit k, 16 lanes/elem, 4 elems/
// wave, 1024 waves = 1/SIMD), h all-gather via 10 independent ds_bpermute
// (single ~40cy latency layer, no LDS write->read RAW), and a common-
// denominator c-update needing only 5 exp2 + 2 rcp per step:
//   c' = (c*(1+pi)(1+pg) + (1-pg)(1+pf)) * rcp((1+pf)(1+pi)(1+pg))
//   h  = (1-pc) * rcp((1+po)(1+pc)),  pc = exp2(-2L*c')
// Weights prescaled by -L (i,f,o) / -2L (g) so dots emit exp2 args directly.
// NOTE (model update): v_pk_fma_f32 is 4cy on CDNA4 (fp32 peak 157.3 TF is
// the scalar rate) -> packing fp32 saves no issue cycles; scalar fma is used.

#define NLOG2E (-1.4426950408889634f)

typedef float f4 __attribute__((ext_vector_type(4)));

__device__ __forceinline__ float bperm(int byteaddr, float v) {
    return __int_as_float(__builtin_amdgcn_ds_bpermute(byteaddr, __float_as_int(v)));
}

__global__ __launch_bounds__(256, 1) void WeatherLSTM_kernel(
    const float* __restrict__ x,     // [B, T, 1]
    const float* __restrict__ W_ih,  // [40, 1]
    const float* __restrict__ W_hh,  // [40, 10]
    const float* __restrict__ b_ih,  // [40]
    const float* __restrict__ b_hh,  // [40]
    const float* __restrict__ W_fc,  // [1, 10]
    const float* __restrict__ b_fc,  // [1]
    float* __restrict__ out,         // [B, 1]
    int T)
{
    const int tid  = threadIdx.x;    // 256 = 16 groups of 16 lanes
    const int lane = tid & 63;
    const int k    = tid & 15;       // hidden unit; active iff k < 10
    const int grp  = tid >> 4;
    const long e   = (long)blockIdx.x * 16 + grp;
    const bool act = (k < 10);

    // Prescaled weights: row scale -L (sigmoid gates i,f,o), -2L (tanh gate g)
    float wh[4][10], wx[4], bb[4];
    #pragma unroll
    for (int t = 0; t < 4; ++t) {
        const float s = (t == 2) ? (2.0f * NLOG2E) : NLOG2E;
        const int g = t * 10 + k;
        wx[t] = act ? W_ih[g] * s : 0.0f;
        bb[t] = act ? (b_ih[g] + b_hh[g]) * s : 0.0f;
        #pragma unroll
        for (int j = 0; j < 10; ++j)
            wh[t][j] = act ? W_hh[g * 10 + j] * s : 0.0f;
    }
    // Inactive lanes: a*=0 -> p*=1 -> mg=0 -> c'=(4c)/8=c/2 -> stays 0 from 0;
    // mc=0 -> hown=0 exactly. Their bpermute slots are never read. Safe.

    const int base = (lane & 48) << 2;   // group base for bpermute (bytes)

    float h[10];
    #pragma unroll
    for (int j = 0; j < 10; ++j) h[j] = 0.0f;
    float c = 0.0f, hown = 0.0f;

    const float* xe = x + e * (long)T;
    f4 xv = *reinterpret_cast<const f4*>(xe);
    for (int s0 = 0; s0 < T; s0 += 4) {
        const int snext = (s0 + 4 < T) ? (s0 + 4) : s0;     // clamped prefetch
        const f4 xnext = *reinterpret_cast<const f4*>(xe + snext);
        #pragma unroll
        for (int ss = 0; ss < 4; ++ss) {
            const float xt = xv[ss];

            // 4 gate dots, each split into two independent chains (8 chains)
            float accA[4], accB[4];
            #pragma unroll
            for (int t = 0; t < 4; ++t) {
                accA[t] = fmaf(xt, wx[t], bb[t]);
                accB[t] = h[5] * wh[t][5];
            }
            #pragma unroll
            for (int j = 0; j < 5; ++j) {
                #pragma unroll
                for (int t = 0; t < 4; ++t)
                    accA[t] = fmaf(h[j], wh[t][j], accA[t]);
            }
            #pragma unroll
            for (int j = 6; j < 10; ++j) {
                #pragma unroll
                for (int t = 0; t < 4; ++t)
                    accB[t] = fmaf(h[j], wh[t][j], accB[t]);
            }
            const float pi = __builtin_amdgcn_exp2f(accA[0] + accB[0]);
            const float pf = __builtin_amdgcn_exp2f(accA[1] + accB[1]);
            const float pg = __builtin_amdgcn_exp2f(accA[2] + accB[2]);
            const float po = __builtin_amdgcn_exp2f(accA[3] + accB[3]);

            // c' = (c*(1+pi)(1+pg) + (1-pg)(1+pf)) / ((1+pf)(1+pi)(1+pg))
            const float qi = 1.0f + pi, qf = 1.0f + pf, qg = 1.0f + pg;
            const float mg = 1.0f - pg;
            const float A   = qi * qg;
            const float num = fmaf(c, A, mg * qf);
            c = num * __builtin_amdgcn_rcpf(A * qf);

            // h = (1-pc) / ((1+po)(1+pc)),  pc = exp2(-2L*c)
            const float pc = __builtin_amdgcn_exp2f(c * (2.0f * NLOG2E));
            const float qo = 1.0f + po, qc = 1.0f + pc, mc = 1.0f - pc;
            hown = mc * __builtin_amdgcn_rcpf(qo * qc);

            // h all-gather: 10 independent bpermutes (one latency layer)
            #pragma unroll
            for (int j = 0; j < 10; ++j)
                h[j] = bperm(base + 4 * j, hown);
        }
        xv = xnext;
    }

    if (k == 0) {
        float o = b_fc[0];
        #pragma unroll
        for (int j = 0; j < 10; ++j)
            o = fmaf(h[j], W_fc[j], o);
        out[e] = o;
    }
}

extern "C" void kernel_launch(void* const* d_in, const int* in_sizes, int n_in,
                              void* d_out, int out_size, void* d_ws, size_t ws_size,
                              hipStream_t stream) {
    const float* x    = (const float*)d_in[0];
    const float* W_ih = (const float*)d_in[1];
    const float* W_hh = (const float*)d_in[2];
    const float* b_ih = (const float*)d_in[3];
    const float* b_hh = (const float*)d_in[4];
    const float* W_fc = (const float*)d_in[5];
    const float* b_fc = (const float*)d_in[6];
    float* out = (float*)d_out;

    const int B = out_size;          // 4096
    const int T = in_sizes[0] / B;   // 512

    dim3 grid(B / 16), block(256);   // 16 elems/block, 256 blocks = 1 per CU
    hipLaunchKernelGGL(WeatherLSTM_kernel, grid, block, 0, stream,
                       x, W_ih, W_hh, b_ih, b_hh, W_fc, b_fc, out, T);
}